// Round 17
// baseline (223.368 us; speedup 1.0000x reference)
//
#include <hip/hip_runtime.h>
#include <math.h>

typedef unsigned int uint;
typedef unsigned short ushort;

typedef __bf16 bf16x8 __attribute__((ext_vector_type(8)));
typedef float f32x4 __attribute__((ext_vector_type(4)));
typedef float f32x2 __attribute__((ext_vector_type(2)));

#define MAXNB 512  // n < 65536 -> NB = ceil(n/128) <= 512

// ---------------- bf16 helpers (RNE pack, shift unpack) ----------------

__device__ inline uint bf16rne(float f) {
    uint u = __float_as_uint(f);
    uint r = ((u >> 16) & 1u) + 0x7fffu;
    return (u + r) >> 16;
}
__device__ inline uint packbf2(float a, float b) {
    return bf16rne(a) | (bf16rne(b) << 16);
}
__device__ inline float unhi(uint v) { return __uint_as_float(v & 0xffff0000u); }

// ---------------- graph prep: deterministic bucketed CSR build --------

// fused: [0..NT1) per-tile LDS histogram | [NT1..) weight prep (+ done init)
__global__ __launch_bounds__(256) void k_hist_prep(const int* __restrict__ dst, int E,
                                                   int NT1, ushort* __restrict__ rank,
                                                   int* __restrict__ C, int NB,
                                                   const float* __restrict__ W0,
                                                   const float* __restrict__ W1,
                                                   const float* __restrict__ W2,
                                                   ushort* __restrict__ WT0,
                                                   ushort* __restrict__ WT1,
                                                   ushort* __restrict__ WT2,
                                                   int* __restrict__ done) {
    __shared__ int hist[MAXNB];
    int tid = threadIdx.x, b = blockIdx.x;
    if (b < NT1) {
        for (int i = tid; i < MAXNB; i += 256) hist[i] = 0;
        __syncthreads();
        int e0 = b * 2048;
#pragma unroll
        for (int i = 0; i < 8; ++i) {
            int e = e0 + i * 256 + tid;
            if (e < E) {
                int be = dst[e] >> 7;
                rank[e] = (ushort)atomicAdd(&hist[be], 1);  // LDS atomic
            }
        }
        __syncthreads();
        for (int be = tid; be < NB; be += 256) C[(size_t)be * NT1 + b] = hist[be];
    } else {
        if (b == NT1 && tid == 0) *done = 0;  // ticket counter for k_cscan
        int idx = (b - NT1) * 256 + tid;
        if (idx < 16384) {
            int c = idx >> 7, k = idx & 127;
            WT0[idx] = (ushort)bf16rne(W0[k * 128 + c]);
            WT1[idx] = (ushort)bf16rne(W1[k * 128 + c]);
        } else if (idx < 16384 + 8192) {
            int j = idx - 16384;
            int c = j >> 7, k = j & 127;
            WT2[j] = (c < 40) ? (ushort)bf16rne(W2[k * 40 + c]) : (ushort)0;
        }
    }
}

// per-bucket tile scan; last block to finish also performs the bucket scan
// (fused bscan via threadfence + ticket; R2-verified).
__global__ __launch_bounds__(64) void k_cscan(int* __restrict__ C, int NT1,
                                              int* __restrict__ T, int NB,
                                              int* __restrict__ tbase,
                                              int* __restrict__ cbase,
                                              int* __restrict__ done) {
    int be = blockIdx.x, lane = threadIdx.x;
    size_t base = (size_t)be * NT1;
    int carry = 0;
    for (int c0 = 0; c0 < NT1; c0 += 64) {
        int idx = c0 + lane;
        int v = (idx < NT1) ? C[base + idx] : 0;
        int s = v;
#pragma unroll
        for (int d = 1; d < 64; d <<= 1) {
            int o = __shfl_up(s, d);
            if (lane >= d) s += o;
        }
        if (idx < NT1) C[base + idx] = carry + s - v;
        carry += __shfl(s, 63);
    }
    if (lane == 0) T[be] = carry;
    __threadfence();  // release T before ticket
    int ticket = 0;
    if (lane == 0) ticket = atomicAdd(done, 1);
    ticket = __shfl(ticket, 0);
    if (ticket == NB - 1) {
        __threadfence();  // acquire all T
        int c1 = 0, c2 = 0;
        for (int b0 = 0; b0 < NB; b0 += 64) {
            int idx = b0 + lane;
            int t = (idx < NB) ? T[idx] : 0;
            int u = t + 1024;
            int s1 = t, s2 = u;
#pragma unroll
            for (int d = 1; d < 64; d <<= 1) {
                int o1 = __shfl_up(s1, d), o2 = __shfl_up(s2, d);
                if (lane >= d) { s1 += o1; s2 += o2; }
            }
            if (idx < NB) { tbase[idx] = c1 + s1 - t; cbase[idx] = c2 + s2 - u; }
            c1 += __shfl(s1, 63);
            c2 += __shfl(s2, 63);
        }
        if (lane == 0) { tbase[NB] = c1; *done = 0; }  // reset for graph replay
    }
}

// block per bucket: node counts (LDS) -> 8-padded scan -> offs/ends/dinv.
// Also zeroes csr pad entries (replaces a global memset). Tail zero = 32
// entries (covers the 3-chunk = 24-entry unconditional overread).
__global__ __launch_bounds__(256) void k_p2a(const uint* __restrict__ tmp,
                                             const int* __restrict__ tbase,
                                             const int* __restrict__ cbase,
                                             int* __restrict__ offs, int* __restrict__ ends,
                                             float* __restrict__ dinv, int n,
                                             uint* __restrict__ csr) {
    __shared__ int lcnt[128];
    __shared__ int sinc[128];
    int be = blockIdx.x, tid = threadIdx.x;
    if (tid < 128) lcnt[tid] = 0;
    __syncthreads();
    int j0 = tbase[be], j1 = tbase[be + 1];
    for (int j = j0 + tid; j < j1; j += 256)
        atomicAdd(&lcnt[tmp[j] >> 16], 1);
    __syncthreads();
    if (tid < 128) {
        int cp = (lcnt[tid] + 7) & ~7;
        int lane = tid & 63;
        int s = cp;
#pragma unroll
        for (int d = 1; d < 64; d <<= 1) {
            int o = __shfl_up(s, d);
            if (lane >= d) s += o;
        }
        sinc[tid] = s;  // inclusive within wave
    }
    __syncthreads();
    if (tid < 128) {
        int c = lcnt[tid];
        int cp = (c + 7) & ~7;
        int base = (tid >= 64) ? sinc[63] : 0;
        int og = cbase[be] + base + sinc[tid] - cp;
        int i = be * 128 + tid;
        if (i < n) {
            offs[i] = og;
            ends[i] = og + c;
            dinv[i] = rsqrtf((float)(c + 1));  // +1 self loop
        }
        for (int j = og + c; j < og + cp; ++j) csr[j] = 0;  // in-window pads
    }
    if (tid == 0) {  // unconditional 3-chunk overread tail past bucket's last node
        int endp = cbase[be] + sinc[63] + sinc[127];
        for (int j = 0; j < 32; ++j) csr[endp + j] = 0;
    }
}

// block per bucket: final scatter; csr entry = {src:16 | bf16(w):16}.
// 4-wide batched edges with sched_barrier-pinned phases (R15-verified).
__global__ __launch_bounds__(256) void k_p2b(const uint* __restrict__ tmp,
                                             const int* __restrict__ tbase,
                                             const int* __restrict__ offs,
                                             const float* __restrict__ dinv,
                                             uint* __restrict__ csr) {
    __shared__ int cur[128];
    int be = blockIdx.x, tid = threadIdx.x;
    if (tid < 128) cur[tid] = 0;
    __syncthreads();
    int j0 = tbase[be], j1 = tbase[be + 1];
    int j = j0 + tid;
    for (; j + 768 < j1; j += 1024) {
        uint v0 = tmp[j];            // phase 1: 4 independent tmp loads
        uint v1 = tmp[j + 256];
        uint v2 = tmp[j + 512];
        uint v3 = tmp[j + 768];
        __builtin_amdgcn_sched_barrier(0);
        float sa = dinv[v0 & 0xffffu];  // phase 2: 4 independent dinv gathers
        float sb = dinv[v1 & 0xffffu];
        float sc = dinv[v2 & 0xffffu];
        float sd = dinv[v3 & 0xffffu];
        __builtin_amdgcn_sched_barrier(0);
        int d0 = be * 128 + (int)(v0 >> 16);  // phase 3: cursors + writes
        int d1 = be * 128 + (int)(v1 >> 16);
        int d2 = be * 128 + (int)(v2 >> 16);
        int d3 = be * 128 + (int)(v3 >> 16);
        int r0 = atomicAdd(&cur[v0 >> 16], 1);
        int r1 = atomicAdd(&cur[v1 >> 16], 1);
        int r2 = atomicAdd(&cur[v2 >> 16], 1);
        int r3 = atomicAdd(&cur[v3 >> 16], 1);
        csr[offs[d0] + r0] = (v0 & 0xffffu) | (bf16rne(sa * dinv[d0]) << 16);
        csr[offs[d1] + r1] = (v1 & 0xffffu) | (bf16rne(sb * dinv[d1]) << 16);
        csr[offs[d2] + r2] = (v2 & 0xffffu) | (bf16rne(sc * dinv[d2]) << 16);
        csr[offs[d3] + r3] = (v3 & 0xffffu) | (bf16rne(sd * dinv[d3]) << 16);
    }
    for (; j < j1; j += 256) {
        uint v = tmp[j];
        int s = (int)(v & 0xffffu);
        int dl = (int)(v >> 16);
        int d = be * 128 + dl;
        int r = atomicAdd(&cur[dl], 1);  // LDS atomic
        uint wb = bf16rne(dinv[s] * dinv[d]) << 16;
        csr[offs[d] + r] = (uint)s | wb;
    }
}

// ---------------- layer-0 GEMM body ----------------
__device__ inline void gemm0_body(const float* __restrict__ x,
                                  const __bf16* __restrict__ WT0,
                                  uint* __restrict__ H8, int n, int blk, int tid) {
    int lane = tid & 63, wv = tid >> 6;
    int rbase = blk * 64 + wv * 16;
    if (rbase >= n) return;  // n % 16 == 0
    int m = lane & 15, quad = lane >> 4;

    bf16x8 a[4];
    const float* xrow = x + (size_t)(rbase + m) * 128 + quad * 8;
#pragma unroll
    for (int ks = 0; ks < 4; ++ks) {
        float4 lo = *(const float4*)(xrow + ks * 32);
        float4 hi = *(const float4*)(xrow + ks * 32 + 4);
        union { ushort u[8]; bf16x8 v; } cv;
        cv.u[0] = (ushort)bf16rne(lo.x); cv.u[1] = (ushort)bf16rne(lo.y);
        cv.u[2] = (ushort)bf16rne(lo.z); cv.u[3] = (ushort)bf16rne(lo.w);
        cv.u[4] = (ushort)bf16rne(hi.x); cv.u[5] = (ushort)bf16rne(hi.y);
        cv.u[6] = (ushort)bf16rne(hi.z); cv.u[7] = (ushort)bf16rne(hi.w);
        a[ks] = cv.v;
    }
    f32x4 acc[8];
#pragma unroll
    for (int t = 0; t < 8; ++t) acc[t] = (f32x4){0.f, 0.f, 0.f, 0.f};
#pragma unroll
    for (int t = 0; t < 8; ++t) {
        const __bf16* wrow = WT0 + (size_t)(t * 16 + m) * 128 + quad * 8;
#pragma unroll
        for (int ks = 0; ks < 4; ++ks) {
            bf16x8 b = *(const bf16x8*)(wrow + ks * 32);
            acc[t] = __builtin_amdgcn_mfma_f32_16x16x32_bf16(a[ks], b, acc[t], 0, 0, 0);
        }
    }
#pragma unroll
    for (int t = 0; t < 8; ++t) {
#pragma unroll
        for (int r = 0; r < 4; ++r) {
            float v = acc[t][r];
            int s0 = lane & ~3;
            float v0 = __shfl(v, s0);
            float v1 = __shfl(v, s0 + 1);
            float v2 = __shfl(v, s0 + 2);
            float v3 = __shfl(v, s0 + 3);
            if ((m & 3) == 0) {
                int pk = __builtin_amdgcn_cvt_pk_fp8_f32(v0, v1, 0, false);
                pk = __builtin_amdgcn_cvt_pk_fp8_f32(v2, v3, pk, true);
                int row = rbase + quad * 4 + r;
                H8[(size_t)row * 32 + t * 4 + (m >> 2)] = (uint)pk;
            }
        }
    }
}

// fused: [0..P) edge scatter into tmp (4B entries) | [P..P+G) layer-0 GEMM
__global__ __launch_bounds__(256) void k_place_gemm(const int* __restrict__ src,
                                                    const int* __restrict__ dst, int E,
                                                    int NT1, const ushort* __restrict__ rank,
                                                    const int* __restrict__ C,
                                                    const int* __restrict__ tbase,
                                                    uint* __restrict__ tmp, int P,
                                                    const float* __restrict__ x,
                                                    const __bf16* __restrict__ WT0,
                                                    uint* __restrict__ H8, int n) {
    int b = blockIdx.x;
    if (b < P) {
        int e = b * 256 + threadIdx.x;
        if (e >= E) return;
        int d = dst[e];
        int be = d >> 7, t = e >> 11;
        int pos = tbase[be] + C[(size_t)be * NT1 + t] + (int)rank[e];
        tmp[pos] = (uint)src[e] | ((uint)(d & 127) << 16);
    } else {
        gemm0_body(x, WT0, H8, n, b - P, threadIdx.x);
    }
}

// ---------------- fused aggregate + GEMM, wide-lane gather -------------------
// R16: 4 nodes/wave, 16 lanes x uint2 (8B) per row — same bytes, HALF the
// gather/load instructions per edge (one gather instr now serves 4 nodes,
// 512B/instr). Per-feature accumulation order over edges is unchanged ->
// bit-identical results. 32 nodes/block (8 waves), 8KB LDS, GEMM tiles
// t = w, w+8 over 2 row-groups x F/16 col-groups. 3-chunk + sched_barrier
// structure (R15-verified) retained.
template <int F>  // 128 (layer 1) or 64 (layer 2)
__global__ __launch_bounds__(512, 4) void k_aggemm2(const uint* __restrict__ hb8,
                                                    const int* __restrict__ offs,
                                                    const int* __restrict__ ends,
                                                    const uint* __restrict__ csr,
                                                    const float* __restrict__ dinv,
                                                    const float* __restrict__ bias,
                                                    const __bf16* __restrict__ WT,
                                                    uint* __restrict__ H8, int n) {
    __shared__ __align__(16) uint lds[32 * 64];  // 32 rows x 256B = 8KB
    int tid = threadIdx.x, lane = tid & 63, w = tid >> 6;  // w in [0,8)
    int rbase = blockIdx.x * 32;
    int q = lane >> 4, l16 = lane & 15;
    int wid = rbase + 4 * w + q;

    const uint2* hb2 = (const uint2*)hb8;  // row = 16 uint2 (128 fp8)
    float4 biaA = ((const float4*)bias)[2 * l16];
    float4 biaB = ((const float4*)bias)[2 * l16 + 1];
    float4 acc0 = make_float4(0.f, 0.f, 0.f, 0.f);
    float4 acc1 = make_float4(0.f, 0.f, 0.f, 0.f);
    bool live = wid < n;

    if (live) {
        float di = dinv[wid];
        float dd = di * di;
        uint2 t0 = hb2[(size_t)wid * 16 + l16];
        f32x2 a01 = __builtin_amdgcn_cvt_pk_f32_fp8((int)t0.x, false);
        f32x2 a23 = __builtin_amdgcn_cvt_pk_f32_fp8((int)t0.x, true);
        f32x2 a45 = __builtin_amdgcn_cvt_pk_f32_fp8((int)t0.y, false);
        f32x2 a67 = __builtin_amdgcn_cvt_pk_f32_fp8((int)t0.y, true);
        acc0 = make_float4(a01[0] * dd, a01[1] * dd, a23[0] * dd, a23[1] * dd);
        acc1 = make_float4(a45[0] * dd, a45[1] * dd, a67[0] * dd, a67[1] * dd);
        int e0 = offs[wid];                       // multiple of 8
        int nchunk = (ends[wid] - e0 + 7) >> 3;
        const uint4* csrv = (const uint4*)(csr + e0);  // quarter-uniform addr

        uint P[3][8];
        uint2 G[3][8];
        // phase 1: 3 chunks of csr-line loads (quarter-broadcast, independent)
#pragma unroll
        for (int c = 0; c < 3; ++c) {
            uint4 v0 = csrv[2 * c];
            uint4 v1 = csrv[2 * c + 1];
            P[c][0] = v0.x; P[c][1] = v0.y; P[c][2] = v0.z; P[c][3] = v0.w;
            P[c][4] = v1.x; P[c][5] = v1.y; P[c][6] = v1.z; P[c][7] = v1.w;
        }
        __builtin_amdgcn_sched_barrier(0);
        // phase 2: ALL gathers, 8B/lane (dep only on own P)
#pragma unroll
        for (int c = 0; c < 3; ++c) {
#pragma unroll
            for (int j = 0; j < 8; ++j)
                G[c][j] = hb2[(size_t)(P[c][j] & 0xffffu) * 16 + l16];
        }
        __builtin_amdgcn_sched_barrier(0);
        // phase 3: FMAs; invalid chunks contribute exactly 0 (wgt=0, v finite)
#pragma unroll
        for (int c = 0; c < 3; ++c) {
            bool ok = c < nchunk;
#pragma unroll
            for (int j = 0; j < 8; ++j) {
                float wgt = ok ? unhi(P[c][j]) : 0.f;
                f32x2 g01 = __builtin_amdgcn_cvt_pk_f32_fp8((int)G[c][j].x, false);
                f32x2 g23 = __builtin_amdgcn_cvt_pk_f32_fp8((int)G[c][j].x, true);
                f32x2 g45 = __builtin_amdgcn_cvt_pk_f32_fp8((int)G[c][j].y, false);
                f32x2 g67 = __builtin_amdgcn_cvt_pk_f32_fp8((int)G[c][j].y, true);
                acc0.x = fmaf(wgt, g01[0], acc0.x);
                acc0.y = fmaf(wgt, g01[1], acc0.y);
                acc0.z = fmaf(wgt, g23[0], acc0.z);
                acc0.w = fmaf(wgt, g23[1], acc0.w);
                acc1.x = fmaf(wgt, g45[0], acc1.x);
                acc1.y = fmaf(wgt, g45[1], acc1.y);
                acc1.z = fmaf(wgt, g67[0], acc1.z);
                acc1.w = fmaf(wgt, g67[1], acc1.w);
            }
        }
        // tail (deg > 24, ~1.5% of nodes), serial
        for (int c = 3; c < nchunk; ++c) {
            uint4 v0 = csrv[2 * c];
            uint4 v1 = csrv[2 * c + 1];
            uint p[8] = {v0.x, v0.y, v0.z, v0.w, v1.x, v1.y, v1.z, v1.w};
            uint2 g[8];
#pragma unroll
            for (int j = 0; j < 8; ++j)
                g[j] = hb2[(size_t)(p[j] & 0xffffu) * 16 + l16];
#pragma unroll
            for (int j = 0; j < 8; ++j) {
                float wgt = unhi(p[j]);
                f32x2 g01 = __builtin_amdgcn_cvt_pk_f32_fp8((int)g[j].x, false);
                f32x2 g23 = __builtin_amdgcn_cvt_pk_f32_fp8((int)g[j].x, true);
                f32x2 g45 = __builtin_amdgcn_cvt_pk_f32_fp8((int)g[j].y, false);
                f32x2 g67 = __builtin_amdgcn_cvt_pk_f32_fp8((int)g[j].y, true);
                acc0.x = fmaf(wgt, g01[0], acc0.x);
                acc0.y = fmaf(wgt, g01[1], acc0.y);
                acc0.z = fmaf(wgt, g23[0], acc0.z);
                acc0.w = fmaf(wgt, g23[1], acc0.w);
                acc1.x = fmaf(wgt, g45[0], acc1.x);
                acc1.y = fmaf(wgt, g45[1], acc1.y);
                acc1.z = fmaf(wgt, g67[0], acc1.z);
                acc1.w = fmaf(wgt, g67[1], acc1.w);
            }
        }
    }

    int r = 4 * w + q;
    uint4 o;
    if (live) {
        o.x = packbf2(fmaxf(acc0.x + biaA.x, 0.f), fmaxf(acc0.y + biaA.y, 0.f));
        o.y = packbf2(fmaxf(acc0.z + biaA.z, 0.f), fmaxf(acc0.w + biaA.w, 0.f));
        o.z = packbf2(fmaxf(acc1.x + biaB.x, 0.f), fmaxf(acc1.y + biaB.y, 0.f));
        o.w = packbf2(fmaxf(acc1.z + biaB.z, 0.f), fmaxf(acc1.w + biaB.w, 0.f));
    } else {
        o.x = 0; o.y = 0; o.z = 0; o.w = 0;
    }
    *(uint4*)((char*)lds + r * 256 + ((l16 * 16) ^ ((r & 7) << 4))) = o;

    __syncthreads();

    // ---- GEMM phase: tile t = w, w+8 -> row-group t/NCG, col-group t%NCG ----
    constexpr int NCG = F / 16;  // 8 or 4
    int m = lane & 15, quad = lane >> 4;
    for (int t = w; t < 2 * NCG; t += 8) {
        int rg = t / NCG, cg = t % NCG;
        int rr = rg * 16 + m;
        bf16x8 a[4];
#pragma unroll
        for (int ks = 0; ks < 4; ++ks) {
            int boff = rr * 256 + ((quad * 16 + ks * 64) ^ ((rr & 7) << 4));
            a[ks] = *(const bf16x8*)((const char*)lds + boff);
        }
        f32x4 acc2 = (f32x4){0.f, 0.f, 0.f, 0.f};
        const __bf16* wrow = WT + (size_t)(cg * 16 + m) * 128 + quad * 8;
#pragma unroll
        for (int ks = 0; ks < 4; ++ks) {
            bf16x8 b = *(const bf16x8*)(wrow + ks * 32);
            acc2 = __builtin_amdgcn_mfma_f32_16x16x32_bf16(a[ks], b, acc2, 0, 0, 0);
        }
#pragma unroll
        for (int r4 = 0; r4 < 4; ++r4) {
            float v = acc2[r4];
            int s0 = lane & ~3;
            float v0 = __shfl(v, s0);
            float v1 = __shfl(v, s0 + 1);
            float v2 = __shfl(v, s0 + 2);
            float v3 = __shfl(v, s0 + 3);
            if ((m & 3) == 0) {
                int pk = __builtin_amdgcn_cvt_pk_fp8_f32(v0, v1, 0, false);
                pk = __builtin_amdgcn_cvt_pk_fp8_f32(v2, v3, pk, true);
                int row = rbase + rg * 16 + quad * 4 + r4;
                if (row < n)
                    H8[(size_t)row * (F / 4) + cg * 4 + (m >> 2)] = (uint)pk;
            }
        }
    }
}

// final layer: fp8 h (64 feats = 16 uints = 1 line/edge). wave = 4 nodes x 16
// lanes; 3-chunk pinned wide gather; fused bias+relu+log_softmax over 16-lane
// groups (40 = 10 lanes x 4).
__global__ __launch_bounds__(256) void k_agg40(const uint* __restrict__ hb8,
                                               const int* __restrict__ offs,
                                               const int* __restrict__ ends,
                                               const uint* __restrict__ csr,
                                               const float* __restrict__ dinv,
                                               const float* __restrict__ bias,
                                               float* __restrict__ out, int n) {
    int tid = threadIdx.x;
    int lane = tid & 63;
    int quad = lane >> 4, l16 = lane & 15;
    int wid = blockIdx.x * 16 + ((tid >> 6) << 2) + quad;
    if (wid >= n) return;
    float di = dinv[wid];
    float dd = di * di;
    uint t0 = hb8[(size_t)wid * 16 + l16];
    f32x2 s01 = __builtin_amdgcn_cvt_pk_f32_fp8((int)t0, false);
    f32x2 s23 = __builtin_amdgcn_cvt_pk_f32_fp8((int)t0, true);
    float4 acc = make_float4(s01[0] * dd, s01[1] * dd, s23[0] * dd, s23[1] * dd);
    int e0 = offs[wid];                       // multiple of 8
    int nchunk = (ends[wid] - e0 + 7) >> 3;
    const uint4* csrv = (const uint4*)(csr + e0);

    uint P[3][8], G[3][8];
#pragma unroll
    for (int c = 0; c < 3; ++c) {
        uint4 v0 = csrv[2 * c];
        uint4 v1 = csrv[2 * c + 1];
        P[c][0] = v0.x; P[c][1] = v0.y; P[c][2] = v0.z; P[c][3] = v0.w;
        P[c][4] = v1.x; P[c][5] = v1.y; P[c][6] = v1.z; P[c][7] = v1.w;
    }
    __builtin_amdgcn_sched_barrier(0);
#pragma unroll
    for (int c = 0; c < 3; ++c) {
#pragma unroll
        for (int j = 0; j < 8; ++j)
            G[c][j] = hb8[(size_t)(P[c][j] & 0xffffu) * 16 + l16];
    }
    __builtin_amdgcn_sched_barrier(0);
#pragma unroll
    for (int c = 0; c < 3; ++c) {
        bool ok = c < nchunk;
#pragma unroll
        for (int j = 0; j < 8; ++j) {
            float w = ok ? unhi(P[c][j]) : 0.f;
            f32x2 a01 = __builtin_amdgcn_cvt_pk_f32_fp8((int)G[c][j], false);
            f32x2 a23 = __builtin_amdgcn_cvt_pk_f32_fp8((int)G[c][j], true);
            acc.x = fmaf(w, a01[0], acc.x);
            acc.y = fmaf(w, a01[1], acc.y);
            acc.z = fmaf(w, a23[0], acc.z);
            acc.w = fmaf(w, a23[1], acc.w);
        }
    }
    for (int c = 3; c < nchunk; ++c) {  // tail (deg > 24), serial
        uint4 v0 = csrv[2 * c];
        uint4 v1 = csrv[2 * c + 1];
        uint q[8] = {v0.x, v0.y, v0.z, v0.w, v1.x, v1.y, v1.z, v1.w};
        uint g[8];
#pragma unroll
        for (int j = 0; j < 8; ++j)
            g[j] = hb8[(size_t)(q[j] & 0xffffu) * 16 + l16];
#pragma unroll
        for (int j = 0; j < 8; ++j) {
            float w = unhi(q[j]);
            f32x2 a01 = __builtin_amdgcn_cvt_pk_f32_fp8((int)g[j], false);
            f32x2 a23 = __builtin_amdgcn_cvt_pk_f32_fp8((int)g[j], true);
            acc.x = fmaf(w, a01[0], acc.x);
            acc.y = fmaf(w, a01[1], acc.y);
            acc.z = fmaf(w, a23[0], acc.z);
            acc.w = fmaf(w, a23[1], acc.w);
        }
    }

    bool val = l16 < 10;                       // features l16*4..l16*4+3 valid iff l16<10
    float4 b4 = val ? ((const float4*)bias)[l16] : make_float4(0.f, 0.f, 0.f, 0.f);
    float v0 = val ? fmaxf(acc.x + b4.x, 0.f) : -INFINITY;
    float v1 = val ? fmaxf(acc.y + b4.y, 0.f) : -INFINITY;
    float v2 = val ? fmaxf(acc.z + b4.z, 0.f) : -INFINITY;
    float v3 = val ? fmaxf(acc.w + b4.w, 0.f) : -INFINITY;
    float m = fmaxf(fmaxf(v0, v1), fmaxf(v2, v3));
#pragma unroll
    for (int d = 8; d; d >>= 1) m = fmaxf(m, __shfl_xor(m, d));
    float ex = val ? (expf(v0 - m) + expf(v1 - m) + expf(v2 - m) + expf(v3 - m)) : 0.f;
#pragma unroll
    for (int d = 8; d; d >>= 1) ex += __shfl_xor(ex, d);
    float ls = logf(ex);
    if (val) {
        ((float4*)out)[(size_t)wid * 10 + l16] =
            make_float4(v0 - m - ls, v1 - m - ls, v2 - m - ls, v3 - m - ls);
    }
}

// ---------------- launch ----------------

extern "C" void kernel_launch(void* const* d_in, const int* in_sizes, int n_in,
                              void* d_out, int out_size, void* d_ws, size_t ws_size,
                              hipStream_t stream) {
    const float* x  = (const float*)d_in[0];
    const int*   ei = (const int*)d_in[1];
    const float* W0 = (const float*)d_in[2];
    const float* b0 = (const float*)d_in[3];
    const float* W1 = (const float*)d_in[4];
    const float* b1 = (const float*)d_in[5];
    const float* W2 = (const float*)d_in[6];
    const float* b2 = (const float*)d_in[7];
    float* out = (float*)d_out;

    int n = in_sizes[0] / 128;
    int E = in_sizes[1] / 2;
    const int* srcv = ei;
    const int* dstv = ei + E;
    int NB  = (n + 127) / 128;     // buckets (dst>>7), <= 512
    int NT1 = (E + 2047) / 2048;   // phase-1 tiles
    size_t csr_elems = (size_t)E + 1024 * (size_t)NB + 64;

    char* w = (char*)d_ws;
    auto alloc = [&](size_t bytes) {
        char* p = w;
        w += (bytes + 255) & ~(size_t)255;
        return p;
    };
    uint*   csr    = (uint*)alloc(csr_elems * 4);        // pads zeroed by k_p2a
    int*    C      = (int*)alloc((size_t)NB * NT1 * 4);
    ushort* rank   = (ushort*)alloc((size_t)E * 2);
    uint*   tmp    = (uint*)alloc((size_t)E * 4);        // {src:16|dl:16}
    int*    T      = (int*)alloc((size_t)NB * 4);
    int*    tbase  = (int*)alloc((size_t)(NB + 1) * 4);
    int*    cbase  = (int*)alloc((size_t)NB * 4);
    int*    offs   = (int*)alloc((size_t)n * 4);
    int*    ends   = (int*)alloc((size_t)n * 4);
    float*  dinv   = (float*)alloc((size_t)n * 4);
    uint*   hA8    = (uint*)alloc((size_t)n * 32 * 4);   // n x 128 fp8 (layer-0 h)
    uint*   hB8    = (uint*)alloc((size_t)n * 32 * 4);   // n x 128 fp8 (layer-1 h)
    uint*   hC8    = (uint*)alloc((size_t)n * 16 * 4);   // n x 64 fp8 (layer-2 h)
    ushort* WT0    = (ushort*)alloc(128 * 128 * 2);
    ushort* WT1    = (ushort*)alloc(128 * 128 * 2);
    ushort* WT2    = (ushort*)alloc(64 * 128 * 2);
    int*    done   = (int*)alloc(256);

    int PB = (16384 + 8192 + 255) / 256;       // prep blocks
    k_hist_prep<<<NT1 + PB, 256, 0, stream>>>(dstv, E, NT1, rank, C, NB,
                                              W0, W1, W2, WT0, WT1, WT2, done);
    k_cscan<<<NB, 64, 0, stream>>>(C, NT1, T, NB, tbase, cbase, done);

    int P = (E + 255) / 256;                   // place blocks
    int G = (n + 63) / 64;                     // gemm0 blocks
    k_place_gemm<<<P + G, 256, 0, stream>>>(srcv, dstv, E, NT1, rank, C, tbase, tmp, P,
                                            x, (const __bf16*)WT0, hA8, n);
    k_p2a<<<NB, 256, 0, stream>>>(tmp, tbase, cbase, offs, ends, dinv, n, csr);
    k_p2b<<<NB, 256, 0, stream>>>(tmp, tbase, offs, dinv, csr);

    int G2 = (n + 31) / 32;                    // aggemm2: 32 nodes/block (512 thr)
    int a4blocks = (n + 15) / 16;              // agg40: 16 nodes/block

    // layer 1: agg(h0)+b0+relu -> LDS -> GEMM @ W1 -> h1
    k_aggemm2<128><<<G2, 512, 0, stream>>>(hA8, offs, ends, csr, dinv, b0,
                                           (const __bf16*)WT1, hB8, n);
    // layer 2: agg(h1)+b1+relu -> LDS -> GEMM @ W2 -> h2 (64-padded)
    k_aggemm2<64><<<G2, 512, 0, stream>>>(hB8, offs, ends, csr, dinv, b1,
                                          (const __bf16*)WT2, hC8, n);
    // layer 3: agg(h2)+b2+relu+log_softmax
    k_agg40<<<a4blocks, 256, 0, stream>>>(hC8, offs, ends, csr, dinv, b2, out, n);
}

// Round 18
// 219.770 us; speedup vs baseline: 1.0164x; 1.0164x over previous
//
#include <hip/hip_runtime.h>
#include <math.h>

typedef unsigned int uint;
typedef unsigned short ushort;

typedef __bf16 bf16x8 __attribute__((ext_vector_type(8)));
typedef float f32x4 __attribute__((ext_vector_type(4)));
typedef float f32x2 __attribute__((ext_vector_type(2)));

#define MAXNB 512  // n < 65536 -> NB = ceil(n/128) <= 512

// ---------------- bf16 helpers (RNE pack, shift unpack) ----------------

__device__ inline uint bf16rne(float f) {
    uint u = __float_as_uint(f);
    uint r = ((u >> 16) & 1u) + 0x7fffu;
    return (u + r) >> 16;
}
__device__ inline uint packbf2(float a, float b) {
    return bf16rne(a) | (bf16rne(b) << 16);
}
__device__ inline float unhi(uint v) { return __uint_as_float(v & 0xffff0000u); }

// ---------------- graph prep: deterministic bucketed CSR build --------

// fused: [0..NT1) per-tile LDS histogram | [NT1..) weight prep (+ done init)
__global__ __launch_bounds__(256) void k_hist_prep(const int* __restrict__ dst, int E,
                                                   int NT1, ushort* __restrict__ rank,
                                                   int* __restrict__ C, int NB,
                                                   const float* __restrict__ W0,
                                                   const float* __restrict__ W1,
                                                   const float* __restrict__ W2,
                                                   ushort* __restrict__ WT0,
                                                   ushort* __restrict__ WT1,
                                                   ushort* __restrict__ WT2,
                                                   int* __restrict__ done) {
    __shared__ int hist[MAXNB];
    int tid = threadIdx.x, b = blockIdx.x;
    if (b < NT1) {
        for (int i = tid; i < MAXNB; i += 256) hist[i] = 0;
        __syncthreads();
        int e0 = b * 2048;
#pragma unroll
        for (int i = 0; i < 8; ++i) {
            int e = e0 + i * 256 + tid;
            if (e < E) {
                int be = dst[e] >> 7;
                rank[e] = (ushort)atomicAdd(&hist[be], 1);  // LDS atomic
            }
        }
        __syncthreads();
        for (int be = tid; be < NB; be += 256) C[(size_t)be * NT1 + b] = hist[be];
    } else {
        if (b == NT1 && tid == 0) *done = 0;  // ticket counter for k_cscan
        int idx = (b - NT1) * 256 + tid;
        if (idx < 16384) {
            int c = idx >> 7, k = idx & 127;
            WT0[idx] = (ushort)bf16rne(W0[k * 128 + c]);
            WT1[idx] = (ushort)bf16rne(W1[k * 128 + c]);
        } else if (idx < 16384 + 8192) {
            int j = idx - 16384;
            int c = j >> 7, k = j & 127;
            WT2[j] = (c < 40) ? (ushort)bf16rne(W2[k * 40 + c]) : (ushort)0;
        }
    }
}

// per-bucket tile scan; last block to finish also performs the bucket scan
// (fused bscan via threadfence + ticket; R2-verified).
__global__ __launch_bounds__(64) void k_cscan(int* __restrict__ C, int NT1,
                                              int* __restrict__ T, int NB,
                                              int* __restrict__ tbase,
                                              int* __restrict__ cbase,
                                              int* __restrict__ done) {
    int be = blockIdx.x, lane = threadIdx.x;
    size_t base = (size_t)be * NT1;
    int carry = 0;
    for (int c0 = 0; c0 < NT1; c0 += 64) {
        int idx = c0 + lane;
        int v = (idx < NT1) ? C[base + idx] : 0;
        int s = v;
#pragma unroll
        for (int d = 1; d < 64; d <<= 1) {
            int o = __shfl_up(s, d);
            if (lane >= d) s += o;
        }
        if (idx < NT1) C[base + idx] = carry + s - v;
        carry += __shfl(s, 63);
    }
    if (lane == 0) T[be] = carry;
    __threadfence();  // release T before ticket
    int ticket = 0;
    if (lane == 0) ticket = atomicAdd(done, 1);
    ticket = __shfl(ticket, 0);
    if (ticket == NB - 1) {
        __threadfence();  // acquire all T
        int c1 = 0, c2 = 0;
        for (int b0 = 0; b0 < NB; b0 += 64) {
            int idx = b0 + lane;
            int t = (idx < NB) ? T[idx] : 0;
            int u = t + 1024;
            int s1 = t, s2 = u;
#pragma unroll
            for (int d = 1; d < 64; d <<= 1) {
                int o1 = __shfl_up(s1, d), o2 = __shfl_up(s2, d);
                if (lane >= d) { s1 += o1; s2 += o2; }
            }
            if (idx < NB) { tbase[idx] = c1 + s1 - t; cbase[idx] = c2 + s2 - u; }
            c1 += __shfl(s1, 63);
            c2 += __shfl(s2, 63);
        }
        if (lane == 0) { tbase[NB] = c1; *done = 0; }  // reset for graph replay
    }
}

// block per bucket: node counts (LDS) -> 8-padded scan -> offs/ends/dinv.
// Also zeroes csr pad entries (replaces a global memset). Tail zero = 32
// entries (covers the 3-chunk = 24-entry unconditional overread).
__global__ __launch_bounds__(256) void k_p2a(const uint* __restrict__ tmp,
                                             const int* __restrict__ tbase,
                                             const int* __restrict__ cbase,
                                             int* __restrict__ offs, int* __restrict__ ends,
                                             float* __restrict__ dinv, int n,
                                             uint* __restrict__ csr) {
    __shared__ int lcnt[128];
    __shared__ int sinc[128];
    int be = blockIdx.x, tid = threadIdx.x;
    if (tid < 128) lcnt[tid] = 0;
    __syncthreads();
    int j0 = tbase[be], j1 = tbase[be + 1];
    for (int j = j0 + tid; j < j1; j += 256)
        atomicAdd(&lcnt[tmp[j] >> 16], 1);
    __syncthreads();
    if (tid < 128) {
        int cp = (lcnt[tid] + 7) & ~7;
        int lane = tid & 63;
        int s = cp;
#pragma unroll
        for (int d = 1; d < 64; d <<= 1) {
            int o = __shfl_up(s, d);
            if (lane >= d) s += o;
        }
        sinc[tid] = s;  // inclusive within wave
    }
    __syncthreads();
    if (tid < 128) {
        int c = lcnt[tid];
        int cp = (c + 7) & ~7;
        int base = (tid >= 64) ? sinc[63] : 0;
        int og = cbase[be] + base + sinc[tid] - cp;
        int i = be * 128 + tid;
        if (i < n) {
            offs[i] = og;
            ends[i] = og + c;
            dinv[i] = rsqrtf((float)(c + 1));  // +1 self loop
        }
        for (int j = og + c; j < og + cp; ++j) csr[j] = 0;  // in-window pads
    }
    if (tid == 0) {  // unconditional 3-chunk overread tail past bucket's last node
        int endp = cbase[be] + sinc[63] + sinc[127];
        for (int j = 0; j < 32; ++j) csr[endp + j] = 0;
    }
}

// block per bucket: final scatter; csr entry = {src:16 | bf16(w):16}.
// 4-wide batched edges with sched_barrier-pinned phases (R15-verified).
__global__ __launch_bounds__(256) void k_p2b(const uint* __restrict__ tmp,
                                             const int* __restrict__ tbase,
                                             const int* __restrict__ offs,
                                             const float* __restrict__ dinv,
                                             uint* __restrict__ csr) {
    __shared__ int cur[128];
    int be = blockIdx.x, tid = threadIdx.x;
    if (tid < 128) cur[tid] = 0;
    __syncthreads();
    int j0 = tbase[be], j1 = tbase[be + 1];
    int j = j0 + tid;
    for (; j + 768 < j1; j += 1024) {
        uint v0 = tmp[j];            // phase 1: 4 independent tmp loads
        uint v1 = tmp[j + 256];
        uint v2 = tmp[j + 512];
        uint v3 = tmp[j + 768];
        __builtin_amdgcn_sched_barrier(0);
        float sa = dinv[v0 & 0xffffu];  // phase 2: 4 independent dinv gathers
        float sb = dinv[v1 & 0xffffu];
        float sc = dinv[v2 & 0xffffu];
        float sd = dinv[v3 & 0xffffu];
        __builtin_amdgcn_sched_barrier(0);
        int d0 = be * 128 + (int)(v0 >> 16);  // phase 3: cursors + writes
        int d1 = be * 128 + (int)(v1 >> 16);
        int d2 = be * 128 + (int)(v2 >> 16);
        int d3 = be * 128 + (int)(v3 >> 16);
        int r0 = atomicAdd(&cur[v0 >> 16], 1);
        int r1 = atomicAdd(&cur[v1 >> 16], 1);
        int r2 = atomicAdd(&cur[v2 >> 16], 1);
        int r3 = atomicAdd(&cur[v3 >> 16], 1);
        csr[offs[d0] + r0] = (v0 & 0xffffu) | (bf16rne(sa * dinv[d0]) << 16);
        csr[offs[d1] + r1] = (v1 & 0xffffu) | (bf16rne(sb * dinv[d1]) << 16);
        csr[offs[d2] + r2] = (v2 & 0xffffu) | (bf16rne(sc * dinv[d2]) << 16);
        csr[offs[d3] + r3] = (v3 & 0xffffu) | (bf16rne(sd * dinv[d3]) << 16);
    }
    for (; j < j1; j += 256) {
        uint v = tmp[j];
        int s = (int)(v & 0xffffu);
        int dl = (int)(v >> 16);
        int d = be * 128 + dl;
        int r = atomicAdd(&cur[dl], 1);  // LDS atomic
        uint wb = bf16rne(dinv[s] * dinv[d]) << 16;
        csr[offs[d] + r] = (uint)s | wb;
    }
}

// ---------------- layer-0 GEMM body ----------------
__device__ inline void gemm0_body(const float* __restrict__ x,
                                  const __bf16* __restrict__ WT0,
                                  uint* __restrict__ H8, int n, int blk, int tid) {
    int lane = tid & 63, wv = tid >> 6;
    int rbase = blk * 64 + wv * 16;
    if (rbase >= n) return;  // n % 16 == 0
    int m = lane & 15, quad = lane >> 4;

    bf16x8 a[4];
    const float* xrow = x + (size_t)(rbase + m) * 128 + quad * 8;
#pragma unroll
    for (int ks = 0; ks < 4; ++ks) {
        float4 lo = *(const float4*)(xrow + ks * 32);
        float4 hi = *(const float4*)(xrow + ks * 32 + 4);
        union { ushort u[8]; bf16x8 v; } cv;
        cv.u[0] = (ushort)bf16rne(lo.x); cv.u[1] = (ushort)bf16rne(lo.y);
        cv.u[2] = (ushort)bf16rne(lo.z); cv.u[3] = (ushort)bf16rne(lo.w);
        cv.u[4] = (ushort)bf16rne(hi.x); cv.u[5] = (ushort)bf16rne(hi.y);
        cv.u[6] = (ushort)bf16rne(hi.z); cv.u[7] = (ushort)bf16rne(hi.w);
        a[ks] = cv.v;
    }
    f32x4 acc[8];
#pragma unroll
    for (int t = 0; t < 8; ++t) acc[t] = (f32x4){0.f, 0.f, 0.f, 0.f};
#pragma unroll
    for (int t = 0; t < 8; ++t) {
        const __bf16* wrow = WT0 + (size_t)(t * 16 + m) * 128 + quad * 8;
#pragma unroll
        for (int ks = 0; ks < 4; ++ks) {
            bf16x8 b = *(const bf16x8*)(wrow + ks * 32);
            acc[t] = __builtin_amdgcn_mfma_f32_16x16x32_bf16(a[ks], b, acc[t], 0, 0, 0);
        }
    }
#pragma unroll
    for (int t = 0; t < 8; ++t) {
#pragma unroll
        for (int r = 0; r < 4; ++r) {
            float v = acc[t][r];
            int s0 = lane & ~3;
            float v0 = __shfl(v, s0);
            float v1 = __shfl(v, s0 + 1);
            float v2 = __shfl(v, s0 + 2);
            float v3 = __shfl(v, s0 + 3);
            if ((m & 3) == 0) {
                int pk = __builtin_amdgcn_cvt_pk_fp8_f32(v0, v1, 0, false);
                pk = __builtin_amdgcn_cvt_pk_fp8_f32(v2, v3, pk, true);
                int row = rbase + quad * 4 + r;
                H8[(size_t)row * 32 + t * 4 + (m >> 2)] = (uint)pk;
            }
        }
    }
}

// fused: [0..P) edge scatter into tmp (4B entries) | [P..P+G) layer-0 GEMM
__global__ __launch_bounds__(256) void k_place_gemm(const int* __restrict__ src,
                                                    const int* __restrict__ dst, int E,
                                                    int NT1, const ushort* __restrict__ rank,
                                                    const int* __restrict__ C,
                                                    const int* __restrict__ tbase,
                                                    uint* __restrict__ tmp, int P,
                                                    const float* __restrict__ x,
                                                    const __bf16* __restrict__ WT0,
                                                    uint* __restrict__ H8, int n) {
    int b = blockIdx.x;
    if (b < P) {
        int e = b * 256 + threadIdx.x;
        if (e >= E) return;
        int d = dst[e];
        int be = d >> 7, t = e >> 11;
        int pos = tbase[be] + C[(size_t)be * NT1 + t] + (int)rank[e];
        tmp[pos] = (uint)src[e] | ((uint)(d & 127) << 16);
    } else {
        gemm0_body(x, WT0, H8, n, b - P, threadIdx.x);
    }
}

// ---------------- fused aggregate + GEMM, sched_barrier-pinned wide gather ---
// R11/R15-verified structure: 2 nodes/wave, 32 lanes x 4B, 3 unconditional
// chunks (Poisson(16): deg<=24 covers 98.5%), sched_barrier(0) between
// {csr loads}/{gathers}/{FMAs}. R16's wide-lane variant (half the gather
// instructions, same cache lines) was FLAT -> agg floor is per-edge
// cache-line traffic, not issue count. This is the verified-best form.
template <int F>  // 128 (layer 1) or 64 (layer 2, col-groups 0..3 only)
__global__ __launch_bounds__(512, 4) void k_aggemm2(const uint* __restrict__ hb8,
                                                    const int* __restrict__ offs,
                                                    const int* __restrict__ ends,
                                                    const uint* __restrict__ csr,
                                                    const float* __restrict__ dinv,
                                                    const float* __restrict__ bias,
                                                    const __bf16* __restrict__ WT,
                                                    uint* __restrict__ H8, int n) {
    __shared__ __align__(16) uint lds[16 * 64];  // 16 rows x 256B
    int tid = threadIdx.x, lane = tid & 63, w = tid >> 6;  // w in [0,8)
    int rbase = blockIdx.x * 16;
    int half = lane >> 5, l32 = lane & 31;
    int wid = rbase + 2 * w + half;

    float4 bia = ((const float4*)bias)[l32];
    float4 acc = make_float4(0.f, 0.f, 0.f, 0.f);
    bool live = wid < n;

    if (live) {
        float di = dinv[wid];
        float dd = di * di;
        uint t0 = hb8[(size_t)wid * 32 + l32];
        f32x2 s01 = __builtin_amdgcn_cvt_pk_f32_fp8((int)t0, false);
        f32x2 s23 = __builtin_amdgcn_cvt_pk_f32_fp8((int)t0, true);
        acc = make_float4(s01[0] * dd, s01[1] * dd, s23[0] * dd, s23[1] * dd);
        int e0 = offs[wid];                       // multiple of 8
        int nchunk = (ends[wid] - e0 + 7) >> 3;
        const uint4* csrv = (const uint4*)(csr + e0);

        uint P[3][8], G[3][8];
        // phase 1: 3 chunks of csr-line loads (6x dwordx4, independent)
#pragma unroll
        for (int c = 0; c < 3; ++c) {
            uint4 v0 = csrv[2 * c];
            uint4 v1 = csrv[2 * c + 1];
            P[c][0] = v0.x; P[c][1] = v0.y; P[c][2] = v0.z; P[c][3] = v0.w;
            P[c][4] = v1.x; P[c][5] = v1.y; P[c][6] = v1.z; P[c][7] = v1.w;
        }
        __builtin_amdgcn_sched_barrier(0);  // no gather hoisted above / load sunk below
        // phase 2: ALL gathers (dep only on own P)
#pragma unroll
        for (int c = 0; c < 3; ++c) {
#pragma unroll
            for (int j = 0; j < 8; ++j)
                G[c][j] = hb8[(size_t)(P[c][j] & 0xffffu) * 32 + l32];
        }
        __builtin_amdgcn_sched_barrier(0);  // no FMA before all gathers issued
        // phase 3: FMAs; invalid chunks contribute exactly 0 (wgt=0, v finite)
#pragma unroll
        for (int c = 0; c < 3; ++c) {
            bool ok = c < nchunk;
#pragma unroll
            for (int j = 0; j < 8; ++j) {
                float wgt = ok ? unhi(P[c][j]) : 0.f;
                f32x2 a01 = __builtin_amdgcn_cvt_pk_f32_fp8((int)G[c][j], false);
                f32x2 a23 = __builtin_amdgcn_cvt_pk_f32_fp8((int)G[c][j], true);
                acc.x = fmaf(wgt, a01[0], acc.x);
                acc.y = fmaf(wgt, a01[1], acc.y);
                acc.z = fmaf(wgt, a23[0], acc.z);
                acc.w = fmaf(wgt, a23[1], acc.w);
            }
        }
        // tail (deg > 24, ~1.5% of nodes), serial
        for (int c = 3; c < nchunk; ++c) {
            uint4 v0 = csrv[2 * c];
            uint4 v1 = csrv[2 * c + 1];
            uint q[8] = {v0.x, v0.y, v0.z, v0.w, v1.x, v1.y, v1.z, v1.w};
            uint g[8];
#pragma unroll
            for (int j = 0; j < 8; ++j)
                g[j] = hb8[(size_t)(q[j] & 0xffffu) * 32 + l32];
#pragma unroll
            for (int j = 0; j < 8; ++j) {
                float wgt = unhi(q[j]);
                f32x2 a01 = __builtin_amdgcn_cvt_pk_f32_fp8((int)g[j], false);
                f32x2 a23 = __builtin_amdgcn_cvt_pk_f32_fp8((int)g[j], true);
                acc.x = fmaf(wgt, a01[0], acc.x);
                acc.y = fmaf(wgt, a01[1], acc.y);
                acc.z = fmaf(wgt, a23[0], acc.z);
                acc.w = fmaf(wgt, a23[1], acc.w);
            }
        }
    }

    int r = 2 * w + half;
    uint2 o;
    if (live) {
        o.x = packbf2(fmaxf(acc.x + bia.x, 0.f), fmaxf(acc.y + bia.y, 0.f));
        o.y = packbf2(fmaxf(acc.z + bia.z, 0.f), fmaxf(acc.w + bia.w, 0.f));
    } else {
        o.x = 0; o.y = 0;
    }
    *(uint2*)((char*)lds + r * 256 + ((l32 * 8) ^ ((r & 7) << 4))) = o;

    __syncthreads();

    // ---- GEMM phase: wave w -> col-group w over all 16 rows ----
    constexpr int NCG = F / 16;  // col groups: 8 or 4
    int cg = w;
    if (cg < NCG) {
        int m = lane & 15, quad = lane >> 4;
        bf16x8 a[4];
#pragma unroll
        for (int ks = 0; ks < 4; ++ks) {
            int boff = m * 256 + ((quad * 16 + ks * 64) ^ ((m & 7) << 4));
            a[ks] = *(const bf16x8*)((const char*)lds + boff);
        }
        f32x4 acc2 = (f32x4){0.f, 0.f, 0.f, 0.f};
        const __bf16* wrow = WT + (size_t)(cg * 16 + m) * 128 + quad * 8;
#pragma unroll
        for (int ks = 0; ks < 4; ++ks) {
            bf16x8 b = *(const bf16x8*)(wrow + ks * 32);
            acc2 = __builtin_amdgcn_mfma_f32_16x16x32_bf16(a[ks], b, acc2, 0, 0, 0);
        }
#pragma unroll
        for (int r4 = 0; r4 < 4; ++r4) {
            float v = acc2[r4];
            int s0 = lane & ~3;
            float v0 = __shfl(v, s0);
            float v1 = __shfl(v, s0 + 1);
            float v2 = __shfl(v, s0 + 2);
            float v3 = __shfl(v, s0 + 3);
            if ((m & 3) == 0) {
                int pk = __builtin_amdgcn_cvt_pk_fp8_f32(v0, v1, 0, false);
                pk = __builtin_amdgcn_cvt_pk_fp8_f32(v2, v3, pk, true);
                int row = rbase + quad * 4 + r4;
                if (row < n)
                    H8[(size_t)row * (F / 4) + cg * 4 + (m >> 2)] = (uint)pk;
            }
        }
    }
}

// final layer: fp8 h (64 feats = 16 uints = 1 line/edge). wave = 4 nodes x 16
// lanes; 3-chunk pinned wide gather; fused bias+relu+log_softmax over 16-lane
// groups (40 = 10 lanes x 4).
__global__ __launch_bounds__(256) void k_agg40(const uint* __restrict__ hb8,
                                               const int* __restrict__ offs,
                                               const int* __restrict__ ends,
                                               const uint* __restrict__ csr,
                                               const float* __restrict__ dinv,
                                               const float* __restrict__ bias,
                                               float* __restrict__ out, int n) {
    int tid = threadIdx.x;
    int lane = tid & 63;
    int quad = lane >> 4, l16 = lane & 15;
    int wid = blockIdx.x * 16 + ((tid >> 6) << 2) + quad;
    if (wid >= n) return;
    float di = dinv[wid];
    float dd = di * di;
    uint t0 = hb8[(size_t)wid * 16 + l16];
    f32x2 s01 = __builtin_amdgcn_cvt_pk_f32_fp8((int)t0, false);
    f32x2 s23 = __builtin_amdgcn_cvt_pk_f32_fp8((int)t0, true);
    float4 acc = make_float4(s01[0] * dd, s01[1] * dd, s23[0] * dd, s23[1] * dd);
    int e0 = offs[wid];                       // multiple of 8
    int nchunk = (ends[wid] - e0 + 7) >> 3;
    const uint4* csrv = (const uint4*)(csr + e0);

    uint P[3][8], G[3][8];
#pragma unroll
    for (int c = 0; c < 3; ++c) {
        uint4 v0 = csrv[2 * c];
        uint4 v1 = csrv[2 * c + 1];
        P[c][0] = v0.x; P[c][1] = v0.y; P[c][2] = v0.z; P[c][3] = v0.w;
        P[c][4] = v1.x; P[c][5] = v1.y; P[c][6] = v1.z; P[c][7] = v1.w;
    }
    __builtin_amdgcn_sched_barrier(0);
#pragma unroll
    for (int c = 0; c < 3; ++c) {
#pragma unroll
        for (int j = 0; j < 8; ++j)
            G[c][j] = hb8[(size_t)(P[c][j] & 0xffffu) * 16 + l16];
    }
    __builtin_amdgcn_sched_barrier(0);
#pragma unroll
    for (int c = 0; c < 3; ++c) {
        bool ok = c < nchunk;
#pragma unroll
        for (int j = 0; j < 8; ++j) {
            float w = ok ? unhi(P[c][j]) : 0.f;
            f32x2 a01 = __builtin_amdgcn_cvt_pk_f32_fp8((int)G[c][j], false);
            f32x2 a23 = __builtin_amdgcn_cvt_pk_f32_fp8((int)G[c][j], true);
            acc.x = fmaf(w, a01[0], acc.x);
            acc.y = fmaf(w, a01[1], acc.y);
            acc.z = fmaf(w, a23[0], acc.z);
            acc.w = fmaf(w, a23[1], acc.w);
        }
    }
    for (int c = 3; c < nchunk; ++c) {  // tail (deg > 24), serial
        uint4 v0 = csrv[2 * c];
        uint4 v1 = csrv[2 * c + 1];
        uint q[8] = {v0.x, v0.y, v0.z, v0.w, v1.x, v1.y, v1.z, v1.w};
        uint g[8];
#pragma unroll
        for (int j = 0; j < 8; ++j)
            g[j] = hb8[(size_t)(q[j] & 0xffffu) * 16 + l16];
#pragma unroll
        for (int j = 0; j < 8; ++j) {
            float w = unhi(q[j]);
            f32x2 a01 = __builtin_amdgcn_cvt_pk_f32_fp8((int)g[j], false);
            f32x2 a23 = __builtin_amdgcn_cvt_pk_f32_fp8((int)g[j], true);
            acc.x = fmaf(w, a01[0], acc.x);
            acc.y = fmaf(w, a01[1], acc.y);
            acc.z = fmaf(w, a23[0], acc.z);
            acc.w = fmaf(w, a23[1], acc.w);
        }
    }

    bool val = l16 < 10;                       // features l16*4..l16*4+3 valid iff l16<10
    float4 b4 = val ? ((const float4*)bias)[l16] : make_float4(0.f, 0.f, 0.f, 0.f);
    float v0 = val ? fmaxf(acc.x + b4.x, 0.f) : -INFINITY;
    float v1 = val ? fmaxf(acc.y + b4.y, 0.f) : -INFINITY;
    float v2 = val ? fmaxf(acc.z + b4.z, 0.f) : -INFINITY;
    float v3 = val ? fmaxf(acc.w + b4.w, 0.f) : -INFINITY;
    float m = fmaxf(fmaxf(v0, v1), fmaxf(v2, v3));
#pragma unroll
    for (int d = 8; d; d >>= 1) m = fmaxf(m, __shfl_xor(m, d));
    float ex = val ? (expf(v0 - m) + expf(v1 - m) + expf(v2 - m) + expf(v3 - m)) : 0.f;
#pragma unroll
    for (int d = 8; d; d >>= 1) ex += __shfl_xor(ex, d);
    float ls = logf(ex);
    if (val) {
        ((float4*)out)[(size_t)wid * 10 + l16] =
            make_float4(v0 - m - ls, v1 - m - ls, v2 - m - ls, v3 - m - ls);
    }
}

// ---------------- launch ----------------

extern "C" void kernel_launch(void* const* d_in, const int* in_sizes, int n_in,
                              void* d_out, int out_size, void* d_ws, size_t ws_size,
                              hipStream_t stream) {
    const float* x  = (const float*)d_in[0];
    const int*   ei = (const int*)d_in[1];
    const float* W0 = (const float*)d_in[2];
    const float* b0 = (const float*)d_in[3];
    const float* W1 = (const float*)d_in[4];
    const float* b1 = (const float*)d_in[5];
    const float* W2 = (const float*)d_in[6];
    const float* b2 = (const float*)d_in[7];
    float* out = (float*)d_out;

    int n = in_sizes[0] / 128;
    int E = in_sizes[1] / 2;
    const int* srcv = ei;
    const int* dstv = ei + E;
    int NB  = (n + 127) / 128;     // buckets (dst>>7), <= 512
    int NT1 = (E + 2047) / 2048;   // phase-1 tiles
    size_t csr_elems = (size_t)E + 1024 * (size_t)NB + 64;

    char* w = (char*)d_ws;
    auto alloc = [&](size_t bytes) {
        char* p = w;
        w += (bytes + 255) & ~(size_t)255;
        return p;
    };
    uint*   csr    = (uint*)alloc(csr_elems * 4);        // pads zeroed by k_p2a
    int*    C      = (int*)alloc((size_t)NB * NT1 * 4);
    ushort* rank   = (ushort*)alloc((size_t)E * 2);
    uint*   tmp    = (uint*)alloc((size_t)E * 4);        // {src:16|dl:16}
    int*    T      = (int*)alloc((size_t)NB * 4);
    int*    tbase  = (int*)alloc((size_t)(NB + 1) * 4);
    int*    cbase  = (int*)alloc((size_t)NB * 4);
    int*    offs   = (int*)alloc((size_t)n * 4);
    int*    ends   = (int*)alloc((size_t)n * 4);
    float*  dinv   = (float*)alloc((size_t)n * 4);
    uint*   hA8    = (uint*)alloc((size_t)n * 32 * 4);   // n x 128 fp8 (layer-0 h)
    uint*   hB8    = (uint*)alloc((size_t)n * 32 * 4);   // n x 128 fp8 (layer-1 h)
    uint*   hC8    = (uint*)alloc((size_t)n * 16 * 4);   // n x 64 fp8 (layer-2 h)
    ushort* WT0    = (ushort*)alloc(128 * 128 * 2);
    ushort* WT1    = (ushort*)alloc(128 * 128 * 2);
    ushort* WT2    = (ushort*)alloc(64 * 128 * 2);
    int*    done   = (int*)alloc(256);

    int PB = (16384 + 8192 + 255) / 256;       // prep blocks
    k_hist_prep<<<NT1 + PB, 256, 0, stream>>>(dstv, E, NT1, rank, C, NB,
                                              W0, W1, W2, WT0, WT1, WT2, done);
    k_cscan<<<NB, 64, 0, stream>>>(C, NT1, T, NB, tbase, cbase, done);

    int P = (E + 255) / 256;                   // place blocks
    int G = (n + 63) / 64;                     // gemm0 blocks
    k_place_gemm<<<P + G, 256, 0, stream>>>(srcv, dstv, E, NT1, rank, C, tbase, tmp, P,
                                            x, (const __bf16*)WT0, hA8, n);
    k_p2a<<<NB, 256, 0, stream>>>(tmp, tbase, cbase, offs, ends, dinv, n, csr);
    k_p2b<<<NB, 256, 0, stream>>>(tmp, tbase, offs, dinv, csr);

    int G2 = (n + 15) / 16;                    // aggemm2: 16 nodes/block (512 thr)
    int a4blocks = (n + 15) / 16;              // agg40: 16 nodes/block

    // layer 1: agg(h0)+b0+relu -> LDS -> GEMM @ W1 -> h1
    k_aggemm2<128><<<G2, 512, 0, stream>>>(hA8, offs, ends, csr, dinv, b0,
                                           (const __bf16*)WT1, hB8, n);
    // layer 2: agg(h1)+b1+relu -> LDS -> GEMM @ W2 -> h2 (64-padded)
    k_aggemm2<64><<<G2, 512, 0, stream>>>(hB8, offs, ends, csr, dinv, b1,
                                          (const __bf16*)WT2, hC8, n);
    // layer 3: agg(h2)+b2+relu+log_softmax
    k_agg40<<<a4blocks, 256, 0, stream>>>(hC8, offs, ends, csr, dinv, b2, out, n);
}